// Round 10
// baseline (146.282 us; speedup 1.0000x reference)
//
#include <hip/hip_runtime.h>
#include <math.h>

#define B_ 512
#define T_ 256
#define I_ 7
#define H_ 64
#define L_ 16
#define NCH_ (T_ / L_)
#define L2E 1.44269504089f
#define GUARD2 (-21.64f)

typedef short bf16x8 __attribute__((ext_vector_type(8)));
typedef short short4v __attribute__((ext_vector_type(4)));
typedef float f32x4 __attribute__((ext_vector_type(4)));

__device__ __forceinline__ unsigned short f2bf(float f) {
  unsigned u = __float_as_uint(f);
  u += 0x7fff + ((u >> 16) & 1);          // RNE
  return (unsigned short)(u >> 16);
}
__device__ __forceinline__ float bf2f(unsigned short u) {
  return __uint_as_float(((unsigned)u) << 16);
}
__device__ __forceinline__ float ex2(float x) { return __builtin_amdgcn_exp2f(x); }
__device__ __forceinline__ float lg2(float x) { return __builtin_amdgcn_logf(x); }
// log2(sigmoid(a)) given a already scaled by log2e
__device__ __forceinline__ float logsig2(float a2) {
  return (a2 < GUARD2) ? a2 : -lg2(1.f + ex2(-a2));
}
__device__ __forceinline__ float sig2(float a2) {
  return __fdividef(1.f, 1.f + ex2(-a2));
}

// ---- consumer pack halves (chunk C, t-half th0): v for w0/w2, o for w1/w3 ----
#define PACK_V(C) do {                                                        \
  const float* xp_ = xb + (C) * (L_ * I_);                                    \
  unsigned short vv[8];                                                       \
  _Pragma("unroll") for (int tt = 0; tt < 8; ++tt) {                          \
    const int t = th0 + tt;                                                   \
    float vp = bP;                                                            \
    _Pragma("unroll") for (int jj = 0; jj < 7; ++jj)                          \
      vp = fmaf(xp_[t * 7 + jj], wP[jj], vp);                                 \
    vv[tt] = f2bf(vp);                                                        \
  }                                                                           \
  short4v p0 = {(short)vv[0], (short)vv[1], (short)vv[2], (short)vv[3]};      \
  short4v p1 = {(short)vv[4], (short)vv[5], (short)vv[6], (short)vv[7]};      \
  *(short4v*)&sVT[(C) & 1][lane][th0]     = p0;                               \
  *(short4v*)&sVT[(C) & 1][lane][th0 + 4] = p1;                               \
} while (0)

#define PACK_O(C) do {                                                        \
  const float* xp_ = xb + (C) * (L_ * I_);                                    \
  _Pragma("unroll") for (int tt = 0; tt < 8; ++tt) {                          \
    const int t = th0 + tt;                                                   \
    float op = bP;                                                            \
    _Pragma("unroll") for (int jj = 0; jj < 7; ++jj)                          \
      op = fmaf(xp_[t * 7 + jj], wP[jj], op);                                 \
    sOpre[(C) & 1][t][lane] = f2bf(op);                                       \
  }                                                                           \
} while (0)

// ---- w4/w5: i*k preacts + ik -> sIK (t-half tb); no register carry ----
#define IK_PRE(C) do {                                                        \
  const float* xp_ = xb + (C) * (L_ * I_);                                    \
  _Pragma("unroll") for (int tt = 0; tt < 8; ++tt) {                          \
    const int t = tb + tt;                                                    \
    float xs[7];                                                              \
    _Pragma("unroll") for (int jj = 0; jj < 7; ++jj) xs[jj] = xp_[t * 7 + jj];\
    float ip = bI2, kp = bK;                                                  \
    _Pragma("unroll") for (int jj = 0; jj < 7; ++jj) {                        \
      ip = fmaf(xs[jj], wi2[jj], ip);                                         \
      kp = fmaf(xs[jj], wk[jj], kp);                                          \
    }                                                                         \
    sIK[(C) & 1][t][lane] = ex2(ip) * kp * 0.125f;                            \
  }                                                                           \
} while (0)

// ---- w4/w5: k~ = ik*2^{m-cl}, k^ = ik*2^{cl15-cl}; ik read from sIK (LDS,
// written one region earlier) so no same-region producer handoff ----
#define IK_EXP(C) do {                                                        \
  float cl[16];                                                               \
  _Pragma("unroll") for (int t = 0; t < 16; ++t) cl[t] = sLs[(C) & 1][lane][t]; \
  _Pragma("unroll") for (int t = 1; t < 16; ++t) cl[t] += cl[t - 1];          \
  const float m = cl[7];                                                      \
  const float scl = ex2(cl[15] - m);                                          \
  unsigned short kh[8];                                                       \
  _Pragma("unroll") for (int tt = 0; tt < 8; ++tt) {                          \
    const int t = tb + tt;                                                    \
    const float ik = sIK[(C) & 1][t][lane];                                   \
    const float u = ik * ex2(m - cl[t]);                                      \
    sKt[(C) & 1][t][lane] = f2bf(u);                                          \
    kh[tt] = f2bf(u * scl);                                                   \
  }                                                                           \
  short4v p0 = {(short)kh[0], (short)kh[1], (short)kh[2], (short)kh[3]};      \
  short4v p1 = {(short)kh[4], (short)kh[5], (short)kh[6], (short)kh[7]};      \
  *(short4v*)&sKnT[(C) & 1][lane][tb]     = p0;                               \
  *(short4v*)&sKnT[(C) & 1][lane][tb + 4] = p1;                               \
} while (0)

// ---- w6/w7: f-gate half (t = ftb..ftb+7) -> sLs ----
#define F_HALF(C) do {                                                        \
  const float* xp_ = xb + (C) * (L_ * I_);                                    \
  _Pragma("unroll") for (int tt = 0; tt < 8; ++tt) {                          \
    const int t = ftb + tt;                                                   \
    float fp = bF2;                                                           \
    _Pragma("unroll") for (int jj = 0; jj < 7; ++jj)                          \
      fp = fmaf(xp_[t * 7 + jj], wf2[jj], fp);                                \
    sLs[(C) & 1][lane][t] = logsig2(fp);                                      \
  }                                                                           \
} while (0)

// ---- w6: chunk scalars (2^{cl7}, 2^{cl15}) + Sq + q~ for t0-7 ----
#define SCALQ(C) do {                                                         \
  const float* xp_ = xb + (C) * (L_ * I_);                                    \
  float cl[16];                                                               \
  _Pragma("unroll") for (int t = 0; t < 16; ++t) cl[t] = sLs[(C) & 1][lane][t]; \
  _Pragma("unroll") for (int t = 1; t < 16; ++t) cl[t] += cl[t - 1];          \
  sEM[(C) & 1][lane]   = ex2(cl[7]);                                          \
  sFtot[(C) & 1][lane] = ex2(cl[15]);                                         \
  if (lane < 16) {                                                            \
    float Sqv = wqs[7];                                                       \
    _Pragma("unroll") for (int jj = 0; jj < 7; ++jj)                          \
      Sqv = fmaf(xp_[lane * 7 + jj], wqs[jj], Sqv);                           \
    sSq[(C) & 1][lane] = Sqv;                                                 \
  }                                                                           \
  const float m = cl[7];                                                      \
  _Pragma("unroll") for (int t = 0; t < 8; ++t) {                             \
    float qq = bQ;                                                            \
    _Pragma("unroll") for (int jj = 0; jj < 7; ++jj)                          \
      qq = fmaf(xp_[t * 7 + jj], wq[jj], qq);                                 \
    sQt[(C) & 1][t][lane] = f2bf(qq * ex2(cl[t] - m));                        \
  }                                                                           \
} while (0)

// ---- w7: den-scan (exact fp32, fs = 2^ls) + q~ for t8-15 ----
#define QDEN(C) do {                                                          \
  const float* xp_ = xb + (C) * (L_ * I_);                                    \
  float ls[16], cl[16];                                                       \
  _Pragma("unroll") for (int t = 0; t < 16; ++t) ls[t] = sLs[(C) & 1][lane][t]; \
  _Pragma("unroll") for (int t = 0; t < 16; ++t) {                            \
    nv = fmaf(ex2(ls[t]), nv, sIK[(C) & 1][t][lane]);                         \
    sDen[(C) & 1][t][lane] = nv;                                              \
  }                                                                           \
  cl[0] = ls[0];                                                              \
  _Pragma("unroll") for (int t = 1; t < 16; ++t) cl[t] = cl[t - 1] + ls[t];   \
  const float m = cl[7];                                                      \
  _Pragma("unroll") for (int t = 8; t < 16; ++t) {                            \
    float qq = bQ;                                                            \
    _Pragma("unroll") for (int jj = 0; jj < 7; ++jj)                          \
      qq = fmaf(xp_[t * 7 + jj], wq[jj], qq);                                 \
    sQt[(C) & 1][t][lane] = f2bf(qq * ex2(cl[t] - m));                        \
  }                                                                           \
} while (0)

// SINGLE barrier per chunk (19 regions vs R9's 33), R9-proven per-role
// divergent-barrier shape. Region j:
//   w0-3: full chunk j (S -> private sS -> C0/G -> Num -> h; same-wave DS
//         write->read needs no barrier, validated in R3) + {v|o}-pack(j+1).
//   w4/5: IK_EXP(j+1) (ik via sIK, written region j-1) then IK_PRE(j+2).
//   w6:   SCALQ(j+1) then F_HALF(j+2, t0-7).
//   w7:   QDEN(j+1) then F_HALF(j+2, t8-15).
// All buffers 2-buffered; every cross-wave dep crosses >=1 barrier (parity
// audit in R10 notes). sS fully zeroed once (bf16 junk can be NaN; NaN*0=NaN
// through MFMA -- R4). Per-role loops keep VGPR ~64 (unified union spills, R8).
__global__ __launch_bounds__(512, 4) void mlstm_sb(
    const float* __restrict__ x,
    const float* __restrict__ Cin,
    const float* __restrict__ nin,
    const float* __restrict__ Wq, const float* __restrict__ bq,
    const float* __restrict__ Wk, const float* __restrict__ bk,
    const float* __restrict__ Wv, const float* __restrict__ bv,
    const float* __restrict__ Wi, const float* __restrict__ bi,
    const float* __restrict__ Wf, const float* __restrict__ bf,
    const float* __restrict__ Wo, const float* __restrict__ bo,
    float* __restrict__ hout, float* __restrict__ Cout, float* __restrict__ nout)
{
  const int b    = blockIdx.x;
  const int tid  = threadIdx.x;
  const int lane = tid & 63;
  const int w    = __builtin_amdgcn_readfirstlane(tid >> 6);  // wave 0..7
  const int quad = lane >> 4;
  const int sl   = lane & 15;

  __shared__ __align__(16) unsigned short sQt[2][L_][72];   // q~ [t][c]
  __shared__ __align__(16) unsigned short sKt[2][L_][72];   // k~ [s][c]
  __shared__ __align__(16) unsigned short sKnT[2][H_][40];  // k^T [c][s] (s16..31 = 0)
  __shared__ __align__(16) unsigned short sVT[2][H_][40];   // v [r][s]   (s16..31 = 0)
  __shared__ __align__(16) unsigned short sS[4][L_][32];    // private masked S (16..31 = 0)
  __shared__ __align__(16) unsigned short sC0[H_][72];      // C0*2^m [r][c] (same-wave)
  __shared__ __align__(16) unsigned short sOpre[2][L_][72]; // o preact (base-2) [t][c]
  __shared__ float sDen[2][L_][68];  // n-scan value [t][c]
  __shared__ float sIK[2][L_][H_];   // i*k (scaled) [t][c]
  __shared__ float sLs[2][H_][17];   // log2(sigmoid(f)) [c][t]
  __shared__ float sSq[2][L_];       // sum_r q_t[r]
  __shared__ float sEM[2][H_];       // 2^{cl7}
  __shared__ float sFtot[2][H_];     // 2^{cl15}
  __shared__ float sNv[H_];

  // zero pads: sKnT/sVT cols 16..31 (both buffers), ALL of sS
  for (int idx = tid; idx < 1024; idx += 512) {
    const int r = idx >> 3, d = idx & 7;
    ((unsigned*)sKnT)[r * 20 + 8 + d] = 0;
    ((unsigned*)sVT)[r * 20 + 8 + d]  = 0;
  }
  for (int idx = tid; idx < 1024; idx += 512) ((unsigned*)sS)[idx] = 0;

  const float* __restrict__ xb = x + (size_t)b * T_ * I_;

  if (w < 4) {
    // ============ CONSUMERS (full chunk per region) + pack halves ============
    const int c0  = 16 * w + sl;
    const int th0 = (w < 2) ? 0 : 8;   // w0,w1: t0-7; w2,w3: t8-15
    float wP[7];
    float bP;
    if ((w & 1) == 0) {
#pragma unroll
      for (int jj = 0; jj < 7; ++jj) wP[jj] = Wv[lane * 7 + jj];
      bP = bv[lane];
    } else {
#pragma unroll
      for (int jj = 0; jj < 7; ++jj) wP[jj] = Wo[lane * 7 + jj] * L2E;
      bP = bo[lane] * L2E;
    }
    f32x4 Cacc[4];
#pragma unroll
    for (int ct = 0; ct < 4; ++ct)
#pragma unroll
      for (int reg = 0; reg < 4; ++reg)
        Cacc[ct][reg] =
            Cin[(size_t)b * H_ * H_ + (size_t)(16 * w + 4 * quad + reg) * H_ + 16 * ct + sl];
    if ((w & 1) == 0) PACK_V(0); else PACK_O(0);
    __syncthreads();  // P-2
    __syncthreads();  // P-1
    for (int j = 0; j < NCH_; ++j) {
      const int p = j & 1;
      // ---- S = Q~ K~^T -> private sS ----
      const bf16x8 aQ0 = *(const bf16x8*)&sQt[p][sl][8 * quad];
      const bf16x8 aQ1 = *(const bf16x8*)&sQt[p][sl][32 + 8 * quad];
      const bf16x8 bK0 = *(const bf16x8*)&sKt[p][sl][8 * quad];
      const bf16x8 bK1 = *(const bf16x8*)&sKt[p][sl][32 + 8 * quad];
      f32x4 Sv = {0.f, 0.f, 0.f, 0.f};
      Sv = __builtin_amdgcn_mfma_f32_16x16x32_bf16(aQ0, bK0, Sv, 0, 0, 0);
      Sv = __builtin_amdgcn_mfma_f32_16x16x32_bf16(aQ1, bK1, Sv, 0, 0, 0);
#pragma unroll
      for (int reg = 0; reg < 4; ++reg) {
        const int t = 4 * quad + reg;
        sS[w][t][sl] = f2bf((sl <= t) ? Sv[reg] : 0.f);
      }
      // ---- C0 snapshot + C decay + G (same-wave rows) ----
      const bf16x8 aV = *(const bf16x8*)&sVT[p][c0][8 * quad];
#pragma unroll
      for (int ct = 0; ct < 4; ++ct) {
        const int cc = 16 * ct + sl;
        const float em = sEM[p][cc];
        const float ft = sFtot[p][cc];
#pragma unroll
        for (int reg = 0; reg < 4; ++reg)
          sC0[16 * w + 4 * quad + reg][cc] = f2bf(Cacc[ct][reg] * em);
        Cacc[ct] *= ft;
        const bf16x8 bH = *(const bf16x8*)&sKnT[p][cc][8 * quad];
        Cacc[ct] = __builtin_amdgcn_mfma_f32_16x16x32_bf16(aV, bH, Cacc[ct], 0, 0, 0);
      }
      // ---- pack next chunk (covers sS/sC0 write->read latency) ----
      if (j + 1 < NCH_) { if ((w & 1) == 0) PACK_V(j + 1); else PACK_O(j + 1); }
      // ---- Num = Q~ C0^T + (M.S) V^T (same-wave DS round-trips, no barrier) ----
      const bf16x8 bC0a = *(const bf16x8*)&sC0[c0][8 * quad];
      const bf16x8 bC0b = *(const bf16x8*)&sC0[c0][32 + 8 * quad];
      const bf16x8 aS   = *(const bf16x8*)&sS[w][sl][8 * quad];
      f32x4 Num = {0.f, 0.f, 0.f, 0.f};
      Num = __builtin_amdgcn_mfma_f32_16x16x32_bf16(aQ0, bC0a, Num, 0, 0, 0);
      Num = __builtin_amdgcn_mfma_f32_16x16x32_bf16(aQ1, bC0b, Num, 0, 0, 0);
      Num = __builtin_amdgcn_mfma_f32_16x16x32_bf16(aS, aV, Num, 0, 0, 0);
      // ---- h ----
#pragma unroll
      for (int reg = 0; reg < 4; ++reg) {
        const int t = 4 * quad + reg;
        const float den = sDen[p][t][c0];
        const float idn = __fdividef(1.f, fmaxf(den * sSq[p][t], 1.f));
        const float o   = sig2(bf2f(sOpre[p][t][c0]));
        const float y = Num[reg] * idn;
        const float e = ex2(y * 2.88539008178f);  // e^{2y}
        const float th = 1.f - __fdividef(2.f, e + 1.f);
        hout[(size_t)b * T_ * H_ + (size_t)(j * L_ + t) * H_ + c0] = o * th;
      }
      __syncthreads();  // per-chunk barrier
    }
#pragma unroll
    for (int ct = 0; ct < 4; ++ct)
#pragma unroll
      for (int reg = 0; reg < 4; ++reg)
        Cout[(size_t)b * H_ * H_ + (size_t)(16 * w + 4 * quad + reg) * H_ + 16 * ct + sl] =
            Cacc[ct][reg];
  } else if (w == 4 || w == 5) {
    // ============ i*k producer (t-half tb) ============
    const int tb = (w == 4) ? 0 : 8;
    float wi2[7], wk[7];
#pragma unroll
    for (int jj = 0; jj < 7; ++jj) {
      wi2[jj] = Wi[lane * 7 + jj] * L2E;
      wk[jj]  = Wk[lane * 7 + jj];
    }
    const float bI2 = bi[lane] * L2E, bK = bk[lane];
    IK_PRE(0);
    __syncthreads();  // P-2
    IK_EXP(0);
    IK_PRE(1);
    __syncthreads();  // P-1
    for (int j = 0; j < NCH_; ++j) {
      if (j + 1 < NCH_) IK_EXP(j + 1);
      if (j + 2 < NCH_) IK_PRE(j + 2);
      __syncthreads();
    }
  } else if (w == 6) {
    // ============ SCALQ(j+1) + f-half(j+2, t0-7) ============
    const int ftb = 0;
    float wf2[7], wq[7], wqs[8];
#pragma unroll
    for (int jj = 0; jj < 7; ++jj) {
      wf2[jj] = Wf[lane * 7 + jj] * L2E;
      wq[jj]  = Wq[lane * 7 + jj];
    }
    const float bF2 = bf[lane] * L2E, bQ = bq[lane];
#pragma unroll
    for (int jj = 0; jj < 7; ++jj) {
      float s = wq[jj];
#pragma unroll
      for (int off = 32; off >= 1; off >>= 1) s += __shfl_xor(s, off);
      wqs[jj] = s;
    }
    {
      float s = bQ;
#pragma unroll
      for (int off = 32; off >= 1; off >>= 1) s += __shfl_xor(s, off);
      wqs[7] = s;
    }
    F_HALF(0);
    __syncthreads();  // P-2
    SCALQ(0);
    F_HALF(1);
    __syncthreads();  // P-1
    for (int j = 0; j < NCH_; ++j) {
      if (j + 1 < NCH_) SCALQ(j + 1);
      if (j + 2 < NCH_) F_HALF(j + 2);
      __syncthreads();
    }
  } else {
    // ============ QDEN(j+1) + f-half(j+2, t8-15) ============
    const int ftb = 8;
    float wf2[7], wq[7];
#pragma unroll
    for (int jj = 0; jj < 7; ++jj) {
      wf2[jj] = Wf[lane * 7 + jj] * L2E;
      wq[jj]  = Wq[lane * 7 + jj];
    }
    const float bF2 = bf[lane] * L2E, bQ = bq[lane];
    float nv = nin[(size_t)b * H_ * H_ + lane];
    F_HALF(0);
    __syncthreads();  // P-2
    QDEN(0);
    F_HALF(1);
    __syncthreads();  // P-1
    for (int j = 0; j < NCH_; ++j) {
      if (j + 1 < NCH_) QDEN(j + 1);
      if (j + 2 < NCH_) F_HALF(j + 2);
      __syncthreads();
    }
    sNv[lane] = nv;
  }

  __syncthreads();  // final: sNv ready
  {
    const float nvv = sNv[lane];
#pragma unroll
    for (int k = 0; k < 8; ++k)
      nout[(size_t)b * H_ * H_ + (size_t)(8 * w + k) * H_ + lane] = nvv;
  }
}

extern "C" void kernel_launch(void* const* d_in, const int* in_sizes, int n_in,
                              void* d_out, int out_size, void* d_ws, size_t ws_size,
                              hipStream_t stream) {
  const float* xp  = (const float*)d_in[0];
  const float* Cp  = (const float*)d_in[1];
  const float* np_ = (const float*)d_in[2];

  const float* W[6];
  const float* Bv[6];
  if (n_in >= 15 && in_sizes[4] == 64) {
    for (int g = 0; g < 6; ++g) {
      W[g]  = (const float*)d_in[3 + 2 * g];
      Bv[g] = (const float*)d_in[4 + 2 * g];
    }
  } else {
    for (int g = 0; g < 6; ++g) {
      W[g]  = (const float*)d_in[3 + g];
      Bv[g] = (const float*)d_in[9 + g];
    }
  }

  float* hout = (float*)d_out;
  float* Cout = hout + (size_t)B_ * T_ * H_;
  float* nout = Cout + (size_t)B_ * H_ * H_;

  mlstm_sb<<<dim3(B_), dim3(512), 0, stream>>>(
      xp, Cp, np_,
      W[0], Bv[0], W[1], Bv[1], W[2], Bv[2],
      W[3], Bv[3], W[4], Bv[4], W[5], Bv[5],
      hout, Cout, nout);
}